// Round 1
// baseline (1371.297 us; speedup 1.0000x reference)
//
#include <hip/hip_runtime.h>
#include <hip/hip_bf16.h>
#include <math.h>

// Problem constants
#define E_ 8
#define D_ 2048
#define I_ 4096
#define TOPK_ 2
#define N_ 4096
#define NPAIR (N_*TOPK_)      // 8192 routed pairs
#define BM 128                // token-block rows
#define MAXTB 72              // max token blocks: 64 + 8 (padding)
#define PADMAX 9216           // padded slot upper bound

typedef __attribute__((ext_vector_type(8))) short s8v;       // 8 x bf16 as shorts (MFMA A/B frag)
typedef __attribute__((ext_vector_type(8))) unsigned short us8;
typedef __attribute__((ext_vector_type(4))) float f32x4;

typedef const __attribute__((address_space(1))) void* gvp;
typedef __attribute__((address_space(3))) void* lvp;

__device__ __forceinline__ unsigned short f2bf(float f) {
  union { float f; unsigned int u; } c; c.f = f;
  unsigned int u = c.u;
  u += 0x7fffu + ((u >> 16) & 1u);   // round-to-nearest-even
  return (unsigned short)(u >> 16);
}

// Convert 16 consecutive fp32 -> 16 bf16, write to LDS (2 x 16B stores)
__device__ __forceinline__ void cvt16(const float* __restrict__ src, unsigned short* dst) {
  float4 a = *(const float4*)(src);
  float4 b = *(const float4*)(src + 4);
  float4 c = *(const float4*)(src + 8);
  float4 d = *(const float4*)(src + 12);
  us8 o0, o1;
  o0[0]=f2bf(a.x); o0[1]=f2bf(a.y); o0[2]=f2bf(a.z); o0[3]=f2bf(a.w);
  o0[4]=f2bf(b.x); o0[5]=f2bf(b.y); o0[6]=f2bf(b.z); o0[7]=f2bf(b.w);
  o1[0]=f2bf(c.x); o1[1]=f2bf(c.y); o1[2]=f2bf(c.z); o1[3]=f2bf(c.w);
  o1[4]=f2bf(d.x); o1[5]=f2bf(d.y); o1[6]=f2bf(d.z); o1[7]=f2bf(d.w);
  *(us8*)(dst)     = o0;
  *(us8*)(dst + 8) = o1;
}

// ---------------- Routing: build per-expert compact padded slot lists ----------------
__global__ void route_kernel(const int* __restrict__ idx, const float* __restrict__ ew,
                             int* cnt, int* offs, int* tb, int* ntb,
                             int* perm, float* wgt)
{
  __shared__ int scnt[E_], soff[E_ + 1], scur[E_];
  int t = threadIdx.x;
  if (t < E_) scnt[t] = 0;
  __syncthreads();
  for (int p = t; p < NPAIR; p += blockDim.x) {
    atomicAdd(&scnt[idx[p]], 1);
  }
  __syncthreads();
  if (t == 0) {
    int o = 0;
    for (int e = 0; e < E_; e++) {
      soff[e] = o; scur[e] = o;
      o += ((scnt[e] + BM - 1) / BM) * BM;
    }
    soff[E_] = o;
    int T = 0;
    for (int e = 0; e < E_; e++) {
      int nb = (scnt[e] + BM - 1) / BM;
      for (int rb = 0; rb < nb; rb++) tb[T++] = (e << 16) | rb;
    }
    *ntb = T;
    for (int e = 0; e < E_; e++) { cnt[e] = scnt[e]; offs[e] = soff[e]; }
    offs[E_] = o;
  }
  __syncthreads();
  // padded gap slots: token = -1, weight = 0
  for (int e = 0; e < E_; e++) {
    int start = soff[e] + scnt[e], end = soff[e + 1];
    for (int s = start + t; s < end; s += blockDim.x) { perm[s] = -1; wgt[s] = 0.f; }
  }
  __syncthreads();
  for (int p = t; p < NPAIR; p += blockDim.x) {
    int e = idx[p];
    int pos = atomicAdd(&scur[e], 1);
    perm[pos] = p / TOPK_;     // token row
    wgt[pos]  = ew[p];
  }
}

// ---------------- x fp32 -> bf16 ----------------
__global__ __launch_bounds__(256)
void cvt_kernel(const float* __restrict__ x, unsigned short* __restrict__ xb)
{
  int i = blockIdx.x * blockDim.x + threadIdx.x;
  int base = i * 4;
  float4 v = *(const float4*)(x + base);
  ushort4 o;
  o.x = f2bf(v.x); o.y = f2bf(v.y); o.z = f2bf(v.z); o.w = f2bf(v.w);
  *(ushort4*)(xb + base) = o;
}

// ---------------- Fused gate+up grouped GEMM + SwiGLU -> H (bf16) ----------------
// tile: 128 tokens x 64 I-cols, BK=64, 4 waves (2x2), wave tile 64x32, two B mats
__global__ __launch_bounds__(256)
void gu_kernel(const unsigned short* __restrict__ xb,
               const float* __restrict__ wg, const float* __restrict__ wu,
               const int* __restrict__ tb, const int* __restrict__ ntb,
               const int* __restrict__ offs, const int* __restrict__ perm,
               unsigned short* __restrict__ H)
{
  int bx = blockIdx.x;
  if (bx >= *ntb) return;
  int ent = tb[bx];
  int e = ent >> 16, rb = ent & 0xffff;
  int slotbase = offs[e] + rb * BM;
  int i0 = blockIdx.y * 64;

  __shared__ unsigned short Al[128 * 64];   // 16 KB  [row][k]
  __shared__ unsigned short Bgl[64 * 64];   // 8 KB   [icol][k]
  __shared__ unsigned short Bul[64 * 64];   // 8 KB

  int tid = threadIdx.x;
  int lane = tid & 63, w = tid >> 6;
  int wr = w >> 1, wc = w & 1;

  // A-staging per-lane gathered source pointers (4 global_load_lds issues/wave)
  const unsigned short* asrc[4];
#pragma unroll
  for (int q = 0; q < 4; q++) {
    int r = (w * 4 + q) * 8 + (lane >> 3);
    int tok = perm[slotbase + r];
    if (tok < 0) tok = 0;                   // padded row: harmless real data
    asrc[q] = xb + (size_t)tok * D_ + (lane & 7) * 8;
  }

  // B-staging: thread -> (row, 16-float k chunk)
  int brow = tid >> 2;
  int bk = (tid & 3) * 16;
  const float* gsrc = wg + ((size_t)e * I_ + i0 + brow) * D_ + bk;
  const float* usrc = wu + ((size_t)e * I_ + i0 + brow) * D_ + bk;

  f32x4 accg[4][2], accu[4][2];
#pragma unroll
  for (int m = 0; m < 4; m++)
#pragma unroll
    for (int n = 0; n < 2; n++) {
      accg[m][n] = f32x4{0.f, 0.f, 0.f, 0.f};
      accu[m][n] = f32x4{0.f, 0.f, 0.f, 0.f};
    }

  for (int k0 = 0; k0 < D_; k0 += 64) {
#pragma unroll
    for (int q = 0; q < 4; q++) {
      __builtin_amdgcn_global_load_lds((gvp)(asrc[q] + k0),
                                       (lvp)(&Al[(w * 4 + q) * 512]), 16, 0, 0);
    }
    cvt16(gsrc + k0, &Bgl[brow * 64 + bk]);
    cvt16(usrc + k0, &Bul[brow * 64 + bk]);
    __syncthreads();
#pragma unroll
    for (int kk = 0; kk < 2; kk++) {
      int kb = kk * 32 + (lane >> 4) * 8;
      s8v af[4], bg[2], bu[2];
#pragma unroll
      for (int m = 0; m < 4; m++) {
        int row = wr * 64 + m * 16 + (lane & 15);
        af[m] = *(const s8v*)(&Al[row * 64 + kb]);
      }
#pragma unroll
      for (int n = 0; n < 2; n++) {
        int col = wc * 32 + n * 16 + (lane & 15);
        bg[n] = *(const s8v*)(&Bgl[col * 64 + kb]);
        bu[n] = *(const s8v*)(&Bul[col * 64 + kb]);
      }
#pragma unroll
      for (int m = 0; m < 4; m++)
#pragma unroll
        for (int n = 0; n < 2; n++) {
          accg[m][n] = __builtin_amdgcn_mfma_f32_16x16x32_bf16(af[m], bg[n], accg[m][n], 0, 0, 0);
          accu[m][n] = __builtin_amdgcn_mfma_f32_16x16x32_bf16(af[m], bu[n], accu[m][n], 0, 0, 0);
        }
    }
    __syncthreads();
  }

  // epilogue: h = silu(g)*u -> H[slot][i] bf16
  int colbase = i0 + wc * 32;
#pragma unroll
  for (int m = 0; m < 4; m++) {
#pragma unroll
    for (int r = 0; r < 4; r++) {
      int row = wr * 64 + m * 16 + (lane >> 4) * 4 + r;
      size_t s = (size_t)(slotbase + row) * I_;
#pragma unroll
      for (int n = 0; n < 2; n++) {
        float g = accg[m][n][r];
        float u = accu[m][n][r];
        float h = (g / (1.0f + __expf(-g))) * u;
        H[s + colbase + n * 16 + (lane & 15)] = f2bf(h);
      }
    }
  }
}

// ---------------- Down grouped GEMM + weighted scatter-add ----------------
// tile: 128 slots x 128 D-cols, BK=64, 4 waves (2x2), wave tile 64x64
__global__ __launch_bounds__(256)
void down_kernel(const unsigned short* __restrict__ H,
                 const float* __restrict__ wd,
                 const int* __restrict__ tb, const int* __restrict__ ntb,
                 const int* __restrict__ offs, const int* __restrict__ perm,
                 const float* __restrict__ wgt,
                 float* __restrict__ out)
{
  int bx = blockIdx.x;
  if (bx >= *ntb) return;
  int ent = tb[bx];
  int e = ent >> 16, rb = ent & 0xffff;
  int slotbase = offs[e] + rb * BM;
  int d0 = blockIdx.y * 128;

  __shared__ unsigned short Al[128 * 64];   // 16 KB (H rows)
  __shared__ unsigned short Bl[128 * 64];   // 16 KB (wd rows, cvt'd)

  int tid = threadIdx.x, lane = tid & 63, w = tid >> 6;
  int wr = w >> 1, wc = w & 1;

  const unsigned short* asrc[4];
#pragma unroll
  for (int q = 0; q < 4; q++) {
    int r = (w * 4 + q) * 8 + (lane >> 3);
    asrc[q] = H + (size_t)(slotbase + r) * I_ + (lane & 7) * 8;
  }
  int brow = tid >> 1;
  int bk = (tid & 1) * 32;
  const float* bsrc = wd + ((size_t)e * D_ + d0 + brow) * I_ + bk;

  f32x4 acc[4][4];
#pragma unroll
  for (int m = 0; m < 4; m++)
#pragma unroll
    for (int n = 0; n < 4; n++) acc[m][n] = f32x4{0.f, 0.f, 0.f, 0.f};

  for (int k0 = 0; k0 < I_; k0 += 64) {
#pragma unroll
    for (int q = 0; q < 4; q++) {
      __builtin_amdgcn_global_load_lds((gvp)(asrc[q] + k0),
                                       (lvp)(&Al[(w * 4 + q) * 512]), 16, 0, 0);
    }
    cvt16(bsrc + k0,      &Bl[brow * 64 + bk]);
    cvt16(bsrc + k0 + 16, &Bl[brow * 64 + bk + 16]);
    __syncthreads();
#pragma unroll
    for (int kk = 0; kk < 2; kk++) {
      int kb = kk * 32 + (lane >> 4) * 8;
      s8v af[4], bf[4];
#pragma unroll
      for (int m = 0; m < 4; m++)
        af[m] = *(const s8v*)(&Al[(wr * 64 + m * 16 + (lane & 15)) * 64 + kb]);
#pragma unroll
      for (int n = 0; n < 4; n++)
        bf[n] = *(const s8v*)(&Bl[(wc * 64 + n * 16 + (lane & 15)) * 64 + kb]);
#pragma unroll
      for (int m = 0; m < 4; m++)
#pragma unroll
        for (int n = 0; n < 4; n++)
          acc[m][n] = __builtin_amdgcn_mfma_f32_16x16x32_bf16(af[m], bf[n], acc[m][n], 0, 0, 0);
    }
    __syncthreads();
  }

  // epilogue: out[token] += w * c  (atomic, handles duplicate routing)
#pragma unroll
  for (int m = 0; m < 4; m++) {
#pragma unroll
    for (int r = 0; r < 4; r++) {
      int row = wr * 64 + m * 16 + (lane >> 4) * 4 + r;
      int s = slotbase + row;
      int tok = perm[s];
      if (tok < 0) continue;
      float wv = wgt[s];
      float* op = out + (size_t)tok * D_ + d0 + wc * 64;
#pragma unroll
      for (int n = 0; n < 4; n++) {
        atomicAdd(op + n * 16 + (lane & 15), acc[m][n][r] * wv);
      }
    }
  }
}

extern "C" void kernel_launch(void* const* d_in, const int* in_sizes, int n_in,
                              void* d_out, int out_size, void* d_ws, size_t ws_size,
                              hipStream_t stream)
{
  const float* x  = (const float*)d_in[0];
  const float* ew = (const float*)d_in[1];
  const int*  idx = (const int*)d_in[2];
  // d_in[3] = top_k scalar (compile-time TOPK_)
  const float* wg = (const float*)d_in[4];
  const float* wu = (const float*)d_in[5];
  const float* wd = (const float*)d_in[6];
  float* out = (float*)d_out;

  char* ws = (char*)d_ws;
  int* cnt   = (int*)(ws);
  int* ntb   = (int*)(ws + 64);
  int* tb    = (int*)(ws + 128);
  int* offs  = (int*)(ws + 512);
  int* perm  = (int*)(ws + 4096);
  float* wgt = (float*)(ws + 4096 + PADMAX * 4);
  unsigned short* xb = (unsigned short*)(ws + 81920);
  unsigned short* H  = (unsigned short*)(ws + 81920 + (size_t)N_ * D_ * 2);
  // ws needed: 81920 + 16 MB + 72 MB ~= 88 MB

  hipMemsetAsync(d_out, 0, (size_t)N_ * D_ * sizeof(float), stream);
  route_kernel<<<1, 256, 0, stream>>>(idx, ew, cnt, offs, tb, ntb, perm, wgt);
  cvt_kernel<<<(N_ * D_ / 4) / 256, 256, 0, stream>>>(x, xb);
  gu_kernel<<<dim3(MAXTB, I_ / 64), 256, 0, stream>>>(xb, wg, wu, tb, ntb, offs, perm, H);
  down_kernel<<<dim3(MAXTB, D_ / 128), 256, 0, stream>>>(H, wd, tb, ntb, offs, perm, wgt, out);
}

// Round 2
// 941.412 us; speedup vs baseline: 1.4566x; 1.4566x over previous
//
#include <hip/hip_runtime.h>
#include <hip/hip_bf16.h>
#include <math.h>

// Problem constants
#define E_ 8
#define D_ 2048
#define I_ 4096
#define TOPK_ 2
#define N_ 4096
#define NPAIR (N_*TOPK_)
#define BM 128
#define MAXTB 72
#define PADMAX 9216

typedef __attribute__((ext_vector_type(8))) short s8v;
typedef __attribute__((ext_vector_type(8))) unsigned short us8;
typedef __attribute__((ext_vector_type(4))) float f32x4;

typedef const __attribute__((address_space(1))) void* gvp;
typedef __attribute__((address_space(3))) void* lvp;

__device__ __forceinline__ unsigned short f2bf(float f) {
  union { float f; unsigned int u; } c; c.f = f;
  unsigned int u = c.u;
  u += 0x7fffu + ((u >> 16) & 1u);
  return (unsigned short)(u >> 16);
}

// ---------------- Routing ----------------
__global__ void route_kernel(const int* __restrict__ idx, const float* __restrict__ ew,
                             int* cnt, int* offs, int* tb, int* ntb,
                             int* perm, float* wgt)
{
  __shared__ int scnt[E_], soff[E_ + 1], scur[E_];
  int t = threadIdx.x;
  if (t < E_) scnt[t] = 0;
  __syncthreads();
  for (int p = t; p < NPAIR; p += blockDim.x) atomicAdd(&scnt[idx[p]], 1);
  __syncthreads();
  if (t == 0) {
    int o = 0;
    for (int e = 0; e < E_; e++) {
      soff[e] = o; scur[e] = o;
      o += ((scnt[e] + BM - 1) / BM) * BM;
    }
    soff[E_] = o;
    int T = 0;
    for (int e = 0; e < E_; e++) {
      int nb = (scnt[e] + BM - 1) / BM;
      for (int rb = 0; rb < nb; rb++) tb[T++] = (e << 16) | rb;
    }
    *ntb = T;
    for (int e = 0; e < E_; e++) { cnt[e] = scnt[e]; offs[e] = soff[e]; }
    offs[E_] = o;
  }
  __syncthreads();
  for (int e = 0; e < E_; e++) {
    int start = soff[e] + scnt[e], end = soff[e + 1];
    for (int s = start + t; s < end; s += blockDim.x) { perm[s] = -1; wgt[s] = 0.f; }
  }
  __syncthreads();
  for (int p = t; p < NPAIR; p += blockDim.x) {
    int e = idx[p];
    int pos = atomicAdd(&scur[e], 1);
    perm[pos] = p / TOPK_;
    wgt[pos]  = ew[p];
  }
}

// ---------------- fp32 -> bf16 streaming convert (8 elems/thread) ----------------
__global__ __launch_bounds__(256)
void cvt8_kernel(const float* __restrict__ src, unsigned short* __restrict__ dst)
{
  size_t i = ((size_t)blockIdx.x * 256 + threadIdx.x) * 8;
  float4 a = *(const float4*)(src + i);
  float4 b = *(const float4*)(src + i + 4);
  us8 o;
  o[0]=f2bf(a.x); o[1]=f2bf(a.y); o[2]=f2bf(a.z); o[3]=f2bf(a.w);
  o[4]=f2bf(b.x); o[5]=f2bf(b.y); o[6]=f2bf(b.z); o[7]=f2bf(b.w);
  *(us8*)(dst + i) = o;
}

// swizzled source k-offset (elements) for gl_lds staging lane
__device__ __forceinline__ int src_swz(int lane) {
  return (((lane & 7) ^ ((lane >> 3) & 7)) << 3);
}
// swizzled LDS element offset for (row, chunk)
__device__ __forceinline__ int lds_swz(int row, int c) {
  return row * 64 + (((c ^ (row & 7))) << 3);
}

// ---------------- Fused gate+up grouped GEMM + SwiGLU (bf16 weights) ----------------
// tile: 128 tokens x 64 I-cols x {g,u}; BK=64; 4 waves (2x2), wave 64x32 per matrix
__global__ __launch_bounds__(256)
void gu_bf16_kernel(const unsigned short* __restrict__ xb,
                    const unsigned short* __restrict__ wgb,
                    const unsigned short* __restrict__ wub,
                    const int* __restrict__ tb, const int* __restrict__ ntb,
                    const int* __restrict__ offs, const int* __restrict__ perm,
                    unsigned short* __restrict__ H)
{
  __shared__ unsigned short Al[128 * 64];
  __shared__ unsigned short Bgl[64 * 64];
  __shared__ unsigned short Bul[64 * 64];

  // chunked XCD swizzle over flattened grid (4608 % 8 == 0)
  int lid = blockIdx.y * gridDim.x + blockIdx.x;
  int cpx = (gridDim.x * gridDim.y) >> 3;
  int sid = (lid & 7) * cpx + (lid >> 3);
  int bx = sid % gridDim.x;
  int by = sid / gridDim.x;
  if (bx >= *ntb) return;
  int ent = tb[bx];
  int e = ent >> 16, rb = ent & 0xffff;
  int slotbase = offs[e] + rb * BM;
  int i0 = by * 64;

  int tid = threadIdx.x, lane = tid & 63, w = tid >> 6;
  int wr = w >> 1, wc = w & 1;
  int soff = src_swz(lane);

  const unsigned short* asrc[4];
#pragma unroll
  for (int q = 0; q < 4; q++) {
    int r = (w * 4 + q) * 8 + (lane >> 3);
    int tok = perm[slotbase + r];
    if (tok < 0) tok = 0;
    asrc[q] = xb + (size_t)tok * D_ + soff;
  }
  const unsigned short *gsrc[2], *usrc[2];
#pragma unroll
  for (int q = 0; q < 2; q++) {
    int row = w * 16 + q * 8 + (lane >> 3);
    gsrc[q] = wgb + ((size_t)e * I_ + i0 + row) * D_ + soff;
    usrc[q] = wub + ((size_t)e * I_ + i0 + row) * D_ + soff;
  }

  f32x4 accg[4][2], accu[4][2];
#pragma unroll
  for (int m = 0; m < 4; m++)
#pragma unroll
    for (int n = 0; n < 2; n++) {
      accg[m][n] = f32x4{0.f, 0.f, 0.f, 0.f};
      accu[m][n] = f32x4{0.f, 0.f, 0.f, 0.f};
    }

  for (int k0 = 0; k0 < D_; k0 += 64) {
#pragma unroll
    for (int q = 0; q < 4; q++)
      __builtin_amdgcn_global_load_lds((gvp)(asrc[q] + k0), (lvp)(&Al[(w * 4 + q) * 512]), 16, 0, 0);
#pragma unroll
    for (int q = 0; q < 2; q++) {
      __builtin_amdgcn_global_load_lds((gvp)(gsrc[q] + k0), (lvp)(&Bgl[(w * 16 + q * 8) * 64]), 16, 0, 0);
      __builtin_amdgcn_global_load_lds((gvp)(usrc[q] + k0), (lvp)(&Bul[(w * 16 + q * 8) * 64]), 16, 0, 0);
    }
    __syncthreads();
#pragma unroll
    for (int kk = 0; kk < 2; kk++) {
      int c = kk * 4 + (lane >> 4);
      s8v af[4], bg[2], bu[2];
#pragma unroll
      for (int m = 0; m < 4; m++) {
        int row = wr * 64 + m * 16 + (lane & 15);
        af[m] = *(const s8v*)(&Al[lds_swz(row, c)]);
      }
#pragma unroll
      for (int n = 0; n < 2; n++) {
        int col = wc * 32 + n * 16 + (lane & 15);
        bg[n] = *(const s8v*)(&Bgl[lds_swz(col, c)]);
        bu[n] = *(const s8v*)(&Bul[lds_swz(col, c)]);
      }
#pragma unroll
      for (int m = 0; m < 4; m++)
#pragma unroll
        for (int n = 0; n < 2; n++) {
          accg[m][n] = __builtin_amdgcn_mfma_f32_16x16x32_bf16(af[m], bg[n], accg[m][n], 0, 0, 0);
          accu[m][n] = __builtin_amdgcn_mfma_f32_16x16x32_bf16(af[m], bu[n], accu[m][n], 0, 0, 0);
        }
    }
    __syncthreads();
  }

  int colbase = i0 + wc * 32;
#pragma unroll
  for (int m = 0; m < 4; m++) {
#pragma unroll
    for (int r = 0; r < 4; r++) {
      int row = wr * 64 + m * 16 + (lane >> 4) * 4 + r;
      size_t s = (size_t)(slotbase + row) * I_;
#pragma unroll
      for (int n = 0; n < 2; n++) {
        float g = accg[m][n][r];
        float u = accu[m][n][r];
        float h = (g / (1.0f + __expf(-g))) * u;
        H[s + colbase + n * 16 + (lane & 15)] = f2bf(h);
      }
    }
  }
}

// ---------------- Down grouped GEMM + weighted scatter-add (bf16 weights) ----------------
// tile: 128 slots x 128 D-cols; BK=64; 4 waves (2x2), wave 64x64
__global__ __launch_bounds__(256)
void down_bf16_kernel(const unsigned short* __restrict__ H,
                      const unsigned short* __restrict__ wdb,
                      const int* __restrict__ tb, const int* __restrict__ ntb,
                      const int* __restrict__ offs, const int* __restrict__ perm,
                      const float* __restrict__ wgt,
                      float* __restrict__ out)
{
  __shared__ unsigned short Al[128 * 64];
  __shared__ unsigned short Bl[128 * 64];

  int lid = blockIdx.y * gridDim.x + blockIdx.x;
  int cpx = (gridDim.x * gridDim.y) >> 3;
  int sid = (lid & 7) * cpx + (lid >> 3);
  int bx = sid % gridDim.x;
  int by = sid / gridDim.x;
  if (bx >= *ntb) return;
  int ent = tb[bx];
  int e = ent >> 16, rb = ent & 0xffff;
  int slotbase = offs[e] + rb * BM;
  int d0 = by * 128;

  int tid = threadIdx.x, lane = tid & 63, w = tid >> 6;
  int wr = w >> 1, wc = w & 1;
  int soff = src_swz(lane);

  const unsigned short* asrc[4];
#pragma unroll
  for (int q = 0; q < 4; q++) {
    int r = (w * 4 + q) * 8 + (lane >> 3);
    asrc[q] = H + (size_t)(slotbase + r) * I_ + soff;
  }
  const unsigned short* bsrc[4];
#pragma unroll
  for (int q = 0; q < 4; q++) {
    int row = w * 32 + q * 8 + (lane >> 3);
    bsrc[q] = wdb + ((size_t)e * D_ + d0 + row) * I_ + soff;
  }

  f32x4 acc[4][4];
#pragma unroll
  for (int m = 0; m < 4; m++)
#pragma unroll
    for (int n = 0; n < 4; n++) acc[m][n] = f32x4{0.f, 0.f, 0.f, 0.f};

  for (int k0 = 0; k0 < I_; k0 += 64) {
#pragma unroll
    for (int q = 0; q < 4; q++)
      __builtin_amdgcn_global_load_lds((gvp)(asrc[q] + k0), (lvp)(&Al[(w * 4 + q) * 512]), 16, 0, 0);
#pragma unroll
    for (int q = 0; q < 4; q++)
      __builtin_amdgcn_global_load_lds((gvp)(bsrc[q] + k0), (lvp)(&Bl[(w * 32 + q * 8) * 64]), 16, 0, 0);
    __syncthreads();
#pragma unroll
    for (int kk = 0; kk < 2; kk++) {
      int c = kk * 4 + (lane >> 4);
      s8v af[4], bf[4];
#pragma unroll
      for (int m = 0; m < 4; m++) {
        int row = wr * 64 + m * 16 + (lane & 15);
        af[m] = *(const s8v*)(&Al[lds_swz(row, c)]);
      }
#pragma unroll
      for (int n = 0; n < 4; n++) {
        int col = wc * 64 + n * 16 + (lane & 15);
        bf[n] = *(const s8v*)(&Bl[lds_swz(col, c)]);
      }
#pragma unroll
      for (int m = 0; m < 4; m++)
#pragma unroll
        for (int n = 0; n < 4; n++)
          acc[m][n] = __builtin_amdgcn_mfma_f32_16x16x32_bf16(af[m], bf[n], acc[m][n], 0, 0, 0);
    }
    __syncthreads();
  }

#pragma unroll
  for (int m = 0; m < 4; m++) {
#pragma unroll
    for (int r = 0; r < 4; r++) {
      int row = wr * 64 + m * 16 + (lane >> 4) * 4 + r;
      int s = slotbase + row;
      int tok = perm[s];
      if (tok < 0) continue;
      float wv = wgt[s];
      float* op = out + (size_t)tok * D_ + d0 + wc * 64;
#pragma unroll
      for (int n = 0; n < 4; n++)
        atomicAdd(op + n * 16 + (lane & 15), acc[m][n][r] * wv);
    }
  }
}

// =================== Fallback (round-1) path: fp32 weights staged in-kernel ===================
__device__ __forceinline__ void cvt16(const float* __restrict__ src, unsigned short* dst) {
  float4 a = *(const float4*)(src);
  float4 b = *(const float4*)(src + 4);
  float4 c = *(const float4*)(src + 8);
  float4 d = *(const float4*)(src + 12);
  us8 o0, o1;
  o0[0]=f2bf(a.x); o0[1]=f2bf(a.y); o0[2]=f2bf(a.z); o0[3]=f2bf(a.w);
  o0[4]=f2bf(b.x); o0[5]=f2bf(b.y); o0[6]=f2bf(b.z); o0[7]=f2bf(b.w);
  o1[0]=f2bf(c.x); o1[1]=f2bf(c.y); o1[2]=f2bf(c.z); o1[3]=f2bf(c.w);
  o1[4]=f2bf(d.x); o1[5]=f2bf(d.y); o1[6]=f2bf(d.z); o1[7]=f2bf(d.w);
  *(us8*)(dst)     = o0;
  *(us8*)(dst + 8) = o1;
}

__global__ __launch_bounds__(256)
void gu_f32_kernel(const unsigned short* __restrict__ xb,
                   const float* __restrict__ wg, const float* __restrict__ wu,
                   const int* __restrict__ tb, const int* __restrict__ ntb,
                   const int* __restrict__ offs, const int* __restrict__ perm,
                   unsigned short* __restrict__ H)
{
  int bx = blockIdx.x;
  if (bx >= *ntb) return;
  int ent = tb[bx];
  int e = ent >> 16, rb = ent & 0xffff;
  int slotbase = offs[e] + rb * BM;
  int i0 = blockIdx.y * 64;

  __shared__ unsigned short Al[128 * 64];
  __shared__ unsigned short Bgl[64 * 64];
  __shared__ unsigned short Bul[64 * 64];

  int tid = threadIdx.x;
  int lane = tid & 63, w = tid >> 6;
  int wr = w >> 1, wc = w & 1;

  const unsigned short* asrc[4];
#pragma unroll
  for (int q = 0; q < 4; q++) {
    int r = (w * 4 + q) * 8 + (lane >> 3);
    int tok = perm[slotbase + r];
    if (tok < 0) tok = 0;
    asrc[q] = xb + (size_t)tok * D_ + (lane & 7) * 8;
  }
  int brow = tid >> 2;
  int bk = (tid & 3) * 16;
  const float* gsrc = wg + ((size_t)e * I_ + i0 + brow) * D_ + bk;
  const float* usrc = wu + ((size_t)e * I_ + i0 + brow) * D_ + bk;

  f32x4 accg[4][2], accu[4][2];
#pragma unroll
  for (int m = 0; m < 4; m++)
#pragma unroll
    for (int n = 0; n < 2; n++) {
      accg[m][n] = f32x4{0.f, 0.f, 0.f, 0.f};
      accu[m][n] = f32x4{0.f, 0.f, 0.f, 0.f};
    }

  for (int k0 = 0; k0 < D_; k0 += 64) {
#pragma unroll
    for (int q = 0; q < 4; q++)
      __builtin_amdgcn_global_load_lds((gvp)(asrc[q] + k0), (lvp)(&Al[(w * 4 + q) * 512]), 16, 0, 0);
    cvt16(gsrc + k0, &Bgl[brow * 64 + bk]);
    cvt16(usrc + k0, &Bul[brow * 64 + bk]);
    __syncthreads();
#pragma unroll
    for (int kk = 0; kk < 2; kk++) {
      int kb = kk * 32 + (lane >> 4) * 8;
      s8v af[4], bg[2], bu[2];
#pragma unroll
      for (int m = 0; m < 4; m++)
        af[m] = *(const s8v*)(&Al[(wr * 64 + m * 16 + (lane & 15)) * 64 + kb]);
#pragma unroll
      for (int n = 0; n < 2; n++) {
        int col = wc * 32 + n * 16 + (lane & 15);
        bg[n] = *(const s8v*)(&Bgl[col * 64 + kb]);
        bu[n] = *(const s8v*)(&Bul[col * 64 + kb]);
      }
#pragma unroll
      for (int m = 0; m < 4; m++)
#pragma unroll
        for (int n = 0; n < 2; n++) {
          accg[m][n] = __builtin_amdgcn_mfma_f32_16x16x32_bf16(af[m], bg[n], accg[m][n], 0, 0, 0);
          accu[m][n] = __builtin_amdgcn_mfma_f32_16x16x32_bf16(af[m], bu[n], accu[m][n], 0, 0, 0);
        }
    }
    __syncthreads();
  }

  int colbase = i0 + wc * 32;
#pragma unroll
  for (int m = 0; m < 4; m++) {
#pragma unroll
    for (int r = 0; r < 4; r++) {
      int row = wr * 64 + m * 16 + (lane >> 4) * 4 + r;
      size_t s = (size_t)(slotbase + row) * I_;
#pragma unroll
      for (int n = 0; n < 2; n++) {
        float g = accg[m][n][r];
        float u = accu[m][n][r];
        float h = (g / (1.0f + __expf(-g))) * u;
        H[s + colbase + n * 16 + (lane & 15)] = f2bf(h);
      }
    }
  }
}

__global__ __launch_bounds__(256)
void down_f32_kernel(const unsigned short* __restrict__ H,
                     const float* __restrict__ wd,
                     const int* __restrict__ tb, const int* __restrict__ ntb,
                     const int* __restrict__ offs, const int* __restrict__ perm,
                     const float* __restrict__ wgt,
                     float* __restrict__ out)
{
  int bx = blockIdx.x;
  if (bx >= *ntb) return;
  int ent = tb[bx];
  int e = ent >> 16, rb = ent & 0xffff;
  int slotbase = offs[e] + rb * BM;
  int d0 = blockIdx.y * 128;

  __shared__ unsigned short Al[128 * 64];
  __shared__ unsigned short Bl[128 * 64];

  int tid = threadIdx.x, lane = tid & 63, w = tid >> 6;
  int wr = w >> 1, wc = w & 1;

  const unsigned short* asrc[4];
#pragma unroll
  for (int q = 0; q < 4; q++) {
    int r = (w * 4 + q) * 8 + (lane >> 3);
    asrc[q] = H + (size_t)(slotbase + r) * I_ + (lane & 7) * 8;
  }
  int brow = tid >> 1;
  int bk = (tid & 1) * 32;
  const float* bsrc = wd + ((size_t)e * D_ + d0 + brow) * I_ + bk;

  f32x4 acc[4][4];
#pragma unroll
  for (int m = 0; m < 4; m++)
#pragma unroll
    for (int n = 0; n < 4; n++) acc[m][n] = f32x4{0.f, 0.f, 0.f, 0.f};

  for (int k0 = 0; k0 < I_; k0 += 64) {
#pragma unroll
    for (int q = 0; q < 4; q++)
      __builtin_amdgcn_global_load_lds((gvp)(asrc[q] + k0), (lvp)(&Al[(w * 4 + q) * 512]), 16, 0, 0);
    cvt16(bsrc + k0,      &Bl[brow * 64 + bk]);
    cvt16(bsrc + k0 + 16, &Bl[brow * 64 + bk + 16]);
    __syncthreads();
#pragma unroll
    for (int kk = 0; kk < 2; kk++) {
      int kb = kk * 32 + (lane >> 4) * 8;
      s8v af[4], bf[4];
#pragma unroll
      for (int m = 0; m < 4; m++)
        af[m] = *(const s8v*)(&Al[(wr * 64 + m * 16 + (lane & 15)) * 64 + kb]);
#pragma unroll
      for (int n = 0; n < 4; n++)
        bf[n] = *(const s8v*)(&Bl[(wc * 64 + n * 16 + (lane & 15)) * 64 + kb]);
#pragma unroll
      for (int m = 0; m < 4; m++)
#pragma unroll
        for (int n = 0; n < 4; n++)
          acc[m][n] = __builtin_amdgcn_mfma_f32_16x16x32_bf16(af[m], bf[n], acc[m][n], 0, 0, 0);
    }
    __syncthreads();
  }

#pragma unroll
  for (int m = 0; m < 4; m++) {
#pragma unroll
    for (int r = 0; r < 4; r++) {
      int row = wr * 64 + m * 16 + (lane >> 4) * 4 + r;
      int s = slotbase + row;
      int tok = perm[s];
      if (tok < 0) continue;
      float wv = wgt[s];
      float* op = out + (size_t)tok * D_ + d0 + wc * 64;
#pragma unroll
      for (int n = 0; n < 4; n++)
        atomicAdd(op + n * 16 + (lane & 15), acc[m][n][r] * wv);
    }
  }
}

extern "C" void kernel_launch(void* const* d_in, const int* in_sizes, int n_in,
                              void* d_out, int out_size, void* d_ws, size_t ws_size,
                              hipStream_t stream)
{
  const float* x  = (const float*)d_in[0];
  const float* ew = (const float*)d_in[1];
  const int*  idx = (const int*)d_in[2];
  const float* wg = (const float*)d_in[4];
  const float* wu = (const float*)d_in[5];
  const float* wd = (const float*)d_in[6];
  float* out = (float*)d_out;

  char* ws = (char*)d_ws;
  int* cnt   = (int*)(ws);
  int* ntb   = (int*)(ws + 64);
  int* tb    = (int*)(ws + 128);
  int* offs  = (int*)(ws + 512);
  int* perm  = (int*)(ws + 4096);
  float* wgt = (float*)(ws + 4096 + PADMAX * 4);
  unsigned short* xb = (unsigned short*)(ws + 81920);

  const size_t xb_bytes = (size_t)N_ * D_ * 2;            // 16.78 MB
  const size_t H_bytes  = (size_t)PADMAX * I_ * 2;        // 75.5 MB
  const size_t w_bytes  = (size_t)E_ * I_ * D_ * 2;       // 134.2 MB each
  unsigned short* H   = (unsigned short*)(ws + 81920 + xb_bytes);
  unsigned short* wgb = (unsigned short*)(ws + 81920 + xb_bytes + H_bytes);
  unsigned short* wub = (unsigned short*)((char*)wgb + w_bytes);
  unsigned short* wdb = (unsigned short*)((char*)wub + w_bytes);
  size_t need = 81920 + xb_bytes + H_bytes + 3 * w_bytes; // ~495 MB

  hipMemsetAsync(d_out, 0, (size_t)N_ * D_ * sizeof(float), stream);
  route_kernel<<<1, 256, 0, stream>>>(idx, ew, cnt, offs, tb, ntb, perm, wgt);
  cvt8_kernel<<<(N_ * D_ / 8) / 256, 256, 0, stream>>>(x, xb);

  if (ws_size >= need) {
    const int wblocks = (E_ * I_ * D_ / 8) / 256;  // 32768
    cvt8_kernel<<<wblocks, 256, 0, stream>>>(wg, wgb);
    cvt8_kernel<<<wblocks, 256, 0, stream>>>(wu, wub);
    cvt8_kernel<<<wblocks, 256, 0, stream>>>(wd, wdb);
    gu_bf16_kernel<<<dim3(MAXTB, I_ / 64), 256, 0, stream>>>(xb, wgb, wub, tb, ntb, offs, perm, H);
    down_bf16_kernel<<<dim3(MAXTB, D_ / 128), 256, 0, stream>>>(H, wdb, tb, ntb, offs, perm, wgt, out);
  } else {
    gu_f32_kernel<<<dim3(MAXTB, I_ / 64), 256, 0, stream>>>(xb, wg, wu, tb, ntb, offs, perm, H);
    down_f32_kernel<<<dim3(MAXTB, D_ / 128), 256, 0, stream>>>(H, wd, tb, ntb, offs, perm, wgt, out);
  }
}

// Round 3
// 832.158 us; speedup vs baseline: 1.6479x; 1.1313x over previous
//
#include <hip/hip_runtime.h>
#include <hip/hip_bf16.h>
#include <math.h>

// Problem constants
#define E_ 8
#define D_ 2048
#define I_ 4096
#define TOPK_ 2
#define N_ 4096
#define NPAIR (N_*TOPK_)
#define PADMAX 10240
#define MAXTB256 40
#define MAXTB128 72

typedef __attribute__((ext_vector_type(8))) short s8v;
typedef __attribute__((ext_vector_type(8))) unsigned short us8;
typedef __attribute__((ext_vector_type(4))) float f32x4;
typedef const __attribute__((address_space(1))) void* gvp;
typedef __attribute__((address_space(3))) void* lvp;

__device__ __forceinline__ unsigned short f2bf(float f) {
  union { float f; unsigned int u; } c; c.f = f;
  unsigned int u = c.u;
  u += 0x7fffu + ((u >> 16) & 1u);
  return (unsigned short)(u >> 16);
}

// ---------------- Routing (pad granularity as arg) ----------------
__global__ void route_kernel(const int* __restrict__ idx, const float* __restrict__ ew,
                             int pad,
                             int* cnt, int* offs, int* tb, int* ntb,
                             int* perm, float* wgt)
{
  __shared__ int scnt[E_], soff[E_ + 1], scur[E_];
  int t = threadIdx.x;
  if (t < E_) scnt[t] = 0;
  __syncthreads();
  for (int p = t; p < NPAIR; p += blockDim.x) atomicAdd(&scnt[idx[p]], 1);
  __syncthreads();
  if (t == 0) {
    int o = 0;
    for (int e = 0; e < E_; e++) {
      soff[e] = o; scur[e] = o;
      o += ((scnt[e] + pad - 1) / pad) * pad;
    }
    soff[E_] = o;
    int T = 0;
    for (int e = 0; e < E_; e++) {
      int nb = (scnt[e] + pad - 1) / pad;
      for (int rb = 0; rb < nb; rb++) tb[T++] = (e << 16) | rb;
    }
    *ntb = T;
    for (int e = 0; e < E_; e++) { cnt[e] = scnt[e]; offs[e] = soff[e]; }
    offs[E_] = o;
  }
  __syncthreads();
  for (int e = 0; e < E_; e++) {
    int start = soff[e] + scnt[e], end = soff[e + 1];
    for (int s = start + t; s < end; s += blockDim.x) { perm[s] = -1; wgt[s] = 0.f; }
  }
  __syncthreads();
  for (int p = t; p < NPAIR; p += blockDim.x) {
    int e = idx[p];
    int pos = atomicAdd(&scur[e], 1);
    perm[pos] = p / TOPK_;
    wgt[pos]  = ew[p];
  }
}

// ---------------- fp32 -> bf16 streaming converts ----------------
__global__ __launch_bounds__(256)
void cvt8_kernel(const float* __restrict__ src, unsigned short* __restrict__ dst)
{
  size_t i = ((size_t)blockIdx.x * 256 + threadIdx.x) * 8;
  float4 a = *(const float4*)(src + i);
  float4 b = *(const float4*)(src + i + 4);
  us8 o;
  o[0]=f2bf(a.x); o[1]=f2bf(a.y); o[2]=f2bf(a.z); o[3]=f2bf(a.w);
  o[4]=f2bf(b.x); o[5]=f2bf(b.y); o[6]=f2bf(b.z); o[7]=f2bf(b.w);
  *(us8*)(dst + i) = o;
}

__global__ __launch_bounds__(256)
void cvtw_kernel(const float* __restrict__ s0, const float* __restrict__ s1,
                 const float* __restrict__ s2,
                 unsigned short* __restrict__ d0, unsigned short* __restrict__ d1,
                 unsigned short* __restrict__ d2)
{
  int b = blockIdx.x;
  int which = b >> 15, bi = b & 32767;
  const float* s = which == 0 ? s0 : (which == 1 ? s1 : s2);
  unsigned short* d = which == 0 ? d0 : (which == 1 ? d1 : d2);
  size_t i = ((size_t)bi * 256 + threadIdx.x) * 8;
  float4 a = *(const float4*)(s + i);
  float4 bb = *(const float4*)(s + i + 4);
  us8 o;
  o[0]=f2bf(a.x); o[1]=f2bf(a.y); o[2]=f2bf(a.z); o[3]=f2bf(a.w);
  o[4]=f2bf(bb.x); o[5]=f2bf(bb.y); o[6]=f2bf(bb.z); o[7]=f2bf(bb.w);
  *(us8*)(d + i) = o;
}

// =================== 8-phase 256-tile grouped GEMM machinery ===================
// LDS: smem[65536] ushort = 128 KB. A slabs [2buf][2kh][128vrow][64elem] at 0,
// B slabs same at 32768. vrow v packs rows 2v,2v+1; 16B-chunk at position
// p = c ^ (v&7), logical chunk c = (r&1)*4 + kc  (kc = k 16B-chunk within 32-elem half).
#define A_SLAB(P,KH) (((P)*2+(KH))*8192)
#define B_SLAB(P,KH) (32768 + ((P)*2+(KH))*8192)

#define SB  __builtin_amdgcn_sched_barrier(0)
#define BARR __builtin_amdgcn_s_barrier()
#define VMW(N) asm volatile("s_waitcnt vmcnt(" #N ")" ::: "memory")
#define LGK asm volatile("s_waitcnt lgkmcnt(0)" ::: "memory")

#define LOAD_A(P,KH,MH) { \
  const unsigned short* ap_ = &smem[A_SLAB(P,KH) + aBase + (MH)*2048]; \
  af[0] = *(const s8v*)(ap_);      af[1] = *(const s8v*)(ap_+512); \
  af[2] = *(const s8v*)(ap_+1024); af[3] = *(const s8v*)(ap_+1536); }

#define LOAD_B(P,KH) { \
  const unsigned short* bp_ = &smem[B_SLAB(P,KH) + bBase]; \
  bf[0] = *(const s8v*)(bp_);      bf[1] = *(const s8v*)(bp_+512); \
  bf[2] = *(const s8v*)(bp_+1024); bf[3] = *(const s8v*)(bp_+1536); }

#define STAGE_A(T,KH,P) { \
  __builtin_amdgcn_global_load_lds((gvp)(aptr0 + (T)*64 + (KH)*32), (lvp)(&smem[A_SLAB(P,KH) + (w*2+0)*512]), 16, 0, 0); \
  __builtin_amdgcn_global_load_lds((gvp)(aptr1 + (T)*64 + (KH)*32), (lvp)(&smem[A_SLAB(P,KH) + (w*2+1)*512]), 16, 0, 0); }

#define STAGE_B(T,KH,P) { \
  __builtin_amdgcn_global_load_lds((gvp)(bptr0 + (T)*64 + (KH)*32), (lvp)(&smem[B_SLAB(P,KH) + (w*2+0)*512]), 16, 0, 0); \
  __builtin_amdgcn_global_load_lds((gvp)(bptr1 + (T)*64 + (KH)*32), (lvp)(&smem[B_SLAB(P,KH) + (w*2+1)*512]), 16, 0, 0); }

#define MFMA16(MH) { \
  _Pragma("unroll") for (int m_ = 0; m_ < 4; m_++) \
    _Pragma("unroll") for (int n_ = 0; n_ < 4; n_++) \
      acc[(MH)*4+m_][n_] = __builtin_amdgcn_mfma_f32_16x16x32_bf16(af[m_], bf[n_], acc[(MH)*4+m_][n_], 0, 0, 0); }

// 4 phases per K-tile: (kh0,mh0)(kh0,mh1)(kh1,mh0)(kh1,mh1).
// Stage slots: p0: A-kh1(t+1)->Pn, p1: B-kh1(t+1)->Pn, p2: A-kh0(t+2)->P, p3: B-kh0(t+2)->P.
// Fences: vmcnt(4) before p0 and p2 (vmcnt(0) at last tile's p2). Each slab is
// fenced 2 phases (>=2 barriers) before its first read -> per-wave-vmcnt safe.
#define TILE_PHASES(T, P, Pn, NT_) { \
  if (T) { VMW(4); SB; } \
  LOAD_B(P, 0); LOAD_A(P, 0, 0); \
  if ((T) + 1 < (NT_)) { STAGE_A((T)+1, 1, Pn); } \
  SB; BARR; LGK; SB; \
  __builtin_amdgcn_s_setprio(1); MFMA16(0); __builtin_amdgcn_s_setprio(0); \
  SB; BARR; SB; \
  LOAD_A(P, 0, 1); \
  if ((T) + 1 < (NT_)) { STAGE_B((T)+1, 1, Pn); } \
  SB; BARR; LGK; SB; \
  __builtin_amdgcn_s_setprio(1); MFMA16(1); __builtin_amdgcn_s_setprio(0); \
  SB; BARR; SB; \
  if ((T) == (NT_) - 1) { VMW(0); SB; } else { VMW(4); SB; } \
  LOAD_B(P, 1); LOAD_A(P, 1, 0); \
  if ((T) + 2 < (NT_)) { STAGE_A((T)+2, 0, P); } \
  SB; BARR; LGK; SB; \
  __builtin_amdgcn_s_setprio(1); MFMA16(0); __builtin_amdgcn_s_setprio(0); \
  SB; BARR; SB; \
  LOAD_A(P, 1, 1); \
  if ((T) + 2 < (NT_)) { STAGE_B((T)+2, 0, P); } \
  SB; BARR; LGK; SB; \
  __builtin_amdgcn_s_setprio(1); MFMA16(1); __builtin_amdgcn_s_setprio(0); \
  SB; BARR; SB; }

#define K_LOOP(NT_) { \
  STAGE_A(0,0,0); STAGE_B(0,0,0); STAGE_A(0,1,0); STAGE_B(0,1,0); \
  STAGE_A(1,0,1); STAGE_B(1,0,1); \
  VMW(8); SB; BARR; SB; \
  _Pragma("unroll 1") \
  for (int tt = 0; tt < (NT_)/2; ++tt) { \
    int t0_ = 2*tt, t1_ = 2*tt+1; \
    TILE_PHASES(t0_, 0, 1, NT_); \
    TILE_PHASES(t1_, 1, 0, NT_); \
  } }

// ---------------- gate+up 8-phase: 256 tokens x (128 I-cols x {g,u}) ----------------
__global__ __launch_bounds__(512, 2)
void gu8_kernel(const unsigned short* __restrict__ xb,
                const unsigned short* __restrict__ wgb,
                const unsigned short* __restrict__ wub,
                const int* __restrict__ tb, const int* __restrict__ ntb,
                const int* __restrict__ offs, const int* __restrict__ perm,
                unsigned short* __restrict__ H)
{
  __shared__ unsigned short smem[65536];   // 128 KB

  int nwg = gridDim.x * gridDim.y;
  int lid = blockIdx.y * gridDim.x + blockIdx.x;
  int cpx = nwg >> 3;
  int sid = (lid & 7) * cpx + (lid >> 3);
  int bx = sid % gridDim.x;
  int by = sid / gridDim.x;
  if (bx >= *ntb) return;
  int ent = tb[bx];
  int e = ent >> 16, rb = ent & 0xffff;
  int slotbase = offs[e] + rb * 256;
  int i0 = by * 128;

  int tid = threadIdx.x, lane = tid & 63, w = tid >> 6;
  int wr = w >> 2, wc = w & 3;

  // staging lane constants
  int cS = (lane & 7) ^ (lane >> 3);
  int rrS = 2 * (lane >> 3) + (cS >> 2);
  int kcS = (cS & 3) * 8;
  int ar0 = (w * 2 + 0) * 16 + rrS;
  int tk0 = perm[slotbase + ar0];       if (tk0 < 0) tk0 = 0;
  int tk1 = perm[slotbase + ar0 + 16];  if (tk1 < 0) tk1 = 0;
  const unsigned short* aptr0 = xb + (size_t)tk0 * D_ + kcS;
  const unsigned short* aptr1 = xb + (size_t)tk1 * D_ + kcS;
  // B virtual rows: frag f = w*2+j -> matrix j (even=gate, odd=up), icol grp w
  const unsigned short* bptr0 = wgb + ((size_t)e * I_ + i0 + w * 16 + rrS) * D_ + kcS;
  const unsigned short* bptr1 = wub + ((size_t)e * I_ + i0 + w * 16 + rrS) * D_ + kcS;

  // read lane constants
  int hl = (lane & 15) >> 1;
  int pA = (((lane & 1) * 4 + (lane >> 4)) ^ hl) * 8;
  int aBase = wr * 4096 + hl * 64 + pA;
  int bBase = wc * 2048 + hl * 64 + pA;

  s8v af[4], bf[4];
  f32x4 acc[8][4];
#pragma unroll
  for (int m = 0; m < 8; m++)
#pragma unroll
    for (int n = 0; n < 4; n++) acc[m][n] = f32x4{0.f,0.f,0.f,0.f};

  K_LOOP(32);   // D_/64

  // epilogue: h = silu(g)*u ; acc[m][2p] = gate, acc[m][2p+1] = up (same I-col grp)
#pragma unroll
  for (int m = 0; m < 8; m++) {
#pragma unroll
    for (int r = 0; r < 4; r++) {
      int row = wr * 128 + m * 16 + (lane >> 4) * 4 + r;
      size_t hbase = (size_t)(slotbase + row) * I_ + i0 + (lane & 15);
#pragma unroll
      for (int pr = 0; pr < 2; pr++) {
        float g = acc[m][pr*2][r];
        float u = acc[m][pr*2+1][r];
        float h = (g / (1.0f + __expf(-g))) * u;
        H[hbase + (wc * 2 + pr) * 16] = f2bf(h);
      }
    }
  }
}

// ---------------- down 8-phase: 256 slots x 256 D-cols + weighted scatter ----------------
__global__ __launch_bounds__(512, 2)
void down8_kernel(const unsigned short* __restrict__ H,
                  const unsigned short* __restrict__ wdb,
                  const int* __restrict__ tb, const int* __restrict__ ntb,
                  const int* __restrict__ offs, const int* __restrict__ perm,
                  const float* __restrict__ wgt,
                  float* __restrict__ out)
{
  __shared__ unsigned short smem[65536];

  int nwg = gridDim.x * gridDim.y;
  int lid = blockIdx.y * gridDim.x + blockIdx.x;
  int cpx = nwg >> 3;
  int sid = (lid & 7) * cpx + (lid >> 3);
  int bx = sid % gridDim.x;
  int by = sid / gridDim.x;
  if (bx >= *ntb) return;
  int ent = tb[bx];
  int e = ent >> 16, rb = ent & 0xffff;
  int slotbase = offs[e] + rb * 256;
  int d0 = by * 256;

  int tid = threadIdx.x, lane = tid & 63, w = tid >> 6;
  int wr = w >> 2, wc = w & 3;

  int cS = (lane & 7) ^ (lane >> 3);
  int rrS = 2 * (lane >> 3) + (cS >> 2);
  int kcS = (cS & 3) * 8;
  int ar0 = (w * 2 + 0) * 16 + rrS;
  const unsigned short* aptr0 = H + (size_t)(slotbase + ar0) * I_ + kcS;
  const unsigned short* aptr1 = H + (size_t)(slotbase + ar0 + 16) * I_ + kcS;
  const unsigned short* bptr0 = wdb + ((size_t)e * D_ + d0 + (w*2+0)*16 + rrS) * I_ + kcS;
  const unsigned short* bptr1 = wdb + ((size_t)e * D_ + d0 + (w*2+1)*16 + rrS) * I_ + kcS;

  int hl = (lane & 15) >> 1;
  int pA = (((lane & 1) * 4 + (lane >> 4)) ^ hl) * 8;
  int aBase = wr * 4096 + hl * 64 + pA;
  int bBase = wc * 2048 + hl * 64 + pA;

  s8v af[4], bf[4];
  f32x4 acc[8][4];
#pragma unroll
  for (int m = 0; m < 8; m++)
#pragma unroll
    for (int n = 0; n < 4; n++) acc[m][n] = f32x4{0.f,0.f,0.f,0.f};

  K_LOOP(64);   // I_/64

#pragma unroll
  for (int m = 0; m < 8; m++) {
#pragma unroll
    for (int r = 0; r < 4; r++) {
      int row = wr * 128 + m * 16 + (lane >> 4) * 4 + r;
      int s = slotbase + row;
      int tok = perm[s];
      if (tok < 0) continue;
      float wv = wgt[s];
      float* op = out + (size_t)tok * D_ + d0 + wc * 64 + (lane & 15);
#pragma unroll
      for (int n = 0; n < 4; n++)
        atomicAdd(op + n * 16, acc[m][n][r] * wv);
    }
  }
}

// =================== Fallback path (round-1 proven): fp32 weights, BM=128 ===================
__device__ __forceinline__ void cvt16(const float* __restrict__ src, unsigned short* dst) {
  float4 a = *(const float4*)(src);
  float4 b = *(const float4*)(src + 4);
  float4 c = *(const float4*)(src + 8);
  float4 d = *(const float4*)(src + 12);
  us8 o0, o1;
  o0[0]=f2bf(a.x); o0[1]=f2bf(a.y); o0[2]=f2bf(a.z); o0[3]=f2bf(a.w);
  o0[4]=f2bf(b.x); o0[5]=f2bf(b.y); o0[6]=f2bf(b.z); o0[7]=f2bf(b.w);
  o1[0]=f2bf(c.x); o1[1]=f2bf(c.y); o1[2]=f2bf(c.z); o1[3]=f2bf(c.w);
  o1[4]=f2bf(d.x); o1[5]=f2bf(d.y); o1[6]=f2bf(d.z); o1[7]=f2bf(d.w);
  *(us8*)(dst)     = o0;
  *(us8*)(dst + 8) = o1;
}

__global__ __launch_bounds__(256)
void gu_f32_kernel(const unsigned short* __restrict__ xb,
                   const float* __restrict__ wg, const float* __restrict__ wu,
                   const int* __restrict__ tb, const int* __restrict__ ntb,
                   const int* __restrict__ offs, const int* __restrict__ perm,
                   unsigned short* __restrict__ H)
{
  int bx = blockIdx.x;
  if (bx >= *ntb) return;
  int ent = tb[bx];
  int e = ent >> 16, rb = ent & 0xffff;
  int slotbase = offs[e] + rb * 128;
  int i0 = blockIdx.y * 64;

  __shared__ unsigned short Al[128 * 64];
  __shared__ unsigned short Bgl[64 * 64];
  __shared__ unsigned short Bul[64 * 64];

  int tid = threadIdx.x;
  int lane = tid & 63, w = tid >> 6;
  int wr = w >> 1, wc = w & 1;

  const unsigned short* asrc[4];
#pragma unroll
  for (int q = 0; q < 4; q++) {
    int r = (w * 4 + q) * 8 + (lane >> 3);
    int tok = perm[slotbase + r];
    if (tok < 0) tok = 0;
    asrc[q] = xb + (size_t)tok * D_ + (lane & 7) * 8;
  }
  int brow = tid >> 2;
  int bk = (tid & 3) * 16;
  const float* gsrc = wg + ((size_t)e * I_ + i0 + brow) * D_ + bk;
  const float* usrc = wu + ((size_t)e * I_ + i0 + brow) * D_ + bk;

  f32x4 accg[4][2], accu[4][2];
#pragma unroll
  for (int m = 0; m < 4; m++)
#pragma unroll
    for (int n = 0; n < 2; n++) {
      accg[m][n] = f32x4{0.f, 0.f, 0.f, 0.f};
      accu[m][n] = f32x4{0.f, 0.f, 0.f, 0.f};
    }

  for (int k0 = 0; k0 < D_; k0 += 64) {
#pragma unroll
    for (int q = 0; q < 4; q++)
      __builtin_amdgcn_global_load_lds((gvp)(asrc[q] + k0), (lvp)(&Al[(w * 4 + q) * 512]), 16, 0, 0);
    cvt16(gsrc + k0, &Bgl[brow * 64 + bk]);
    cvt16(usrc + k0, &Bul[brow * 64 + bk]);
    __syncthreads();
#pragma unroll
    for (int kk = 0; kk < 2; kk++) {
      int kb = kk * 32 + (lane >> 4) * 8;
      s8v af[4], bg[2], bu[2];
#pragma unroll
      for (int m = 0; m < 4; m++)
        af[m] = *(const s8v*)(&Al[(wr * 64 + m * 16 + (lane & 15)) * 64 + kb]);
#pragma unroll
      for (int n = 0; n < 2; n++) {
        int col = wc * 32 + n * 16 + (lane & 15);
        bg[n] = *(const s8v*)(&Bgl[col * 64 + kb]);
        bu[n] = *(const s8v*)(&Bul[col * 64 + kb]);
      }
#pragma unroll
      for (int m = 0; m < 4; m++)
#pragma unroll
        for (int n = 0; n < 2; n++) {
          accg[m][n] = __builtin_amdgcn_mfma_f32_16x16x32_bf16(af[m], bg[n], accg[m][n], 0, 0, 0);
          accu[m][n] = __builtin_amdgcn_mfma_f32_16x16x32_bf16(af[m], bu[n], accu[m][n], 0, 0, 0);
        }
    }
    __syncthreads();
  }

  int colbase = i0 + wc * 32;
#pragma unroll
  for (int m = 0; m < 4; m++) {
#pragma unroll
    for (int r = 0; r < 4; r++) {
      int row = wr * 64 + m * 16 + (lane >> 4) * 4 + r;
      size_t s = (size_t)(slotbase + row) * I_;
#pragma unroll
      for (int n = 0; n < 2; n++) {
        float g = accg[m][n][r];
        float u = accu[m][n][r];
        float h = (g / (1.0f + __expf(-g))) * u;
        H[s + colbase + n * 16 + (lane & 15)] = f2bf(h);
      }
    }
  }
}

__global__ __launch_bounds__(256)
void down_f32_kernel(const unsigned short* __restrict__ H,
                     const float* __restrict__ wd,
                     const int* __restrict__ tb, const int* __restrict__ ntb,
                     const int* __restrict__ offs, const int* __restrict__ perm,
                     const float* __restrict__ wgt,
                     float* __restrict__ out)
{
  int bx = blockIdx.x;
  if (bx >= *ntb) return;
  int ent = tb[bx];
  int e = ent >> 16, rb = ent & 0xffff;
  int slotbase = offs[e] + rb * 128;
  int d0 = blockIdx.y * 128;

  __shared__ unsigned short Al[128 * 64];
  __shared__ unsigned short Bl[128 * 64];

  int tid = threadIdx.x, lane = tid & 63, w = tid >> 6;
  int wr = w >> 1, wc = w & 1;

  const unsigned short* asrc[4];
#pragma unroll
  for (int q = 0; q < 4; q++) {
    int r = (w * 4 + q) * 8 + (lane >> 3);
    asrc[q] = H + (size_t)(slotbase + r) * I_ + (lane & 7) * 8;
  }
  int brow = tid >> 1;
  int bk = (tid & 1) * 32;
  const float* bsrc = wd + ((size_t)e * D_ + d0 + brow) * I_ + bk;

  f32x4 acc[4][4];
#pragma unroll
  for (int m = 0; m < 4; m++)
#pragma unroll
    for (int n = 0; n < 4; n++) acc[m][n] = f32x4{0.f, 0.f, 0.f, 0.f};

  for (int k0 = 0; k0 < I_; k0 += 64) {
#pragma unroll
    for (int q = 0; q < 4; q++)
      __builtin_amdgcn_global_load_lds((gvp)(asrc[q] + k0), (lvp)(&Al[(w * 4 + q) * 512]), 16, 0, 0);
    cvt16(bsrc + k0,      &Bl[brow * 64 + bk]);
    cvt16(bsrc + k0 + 16, &Bl[brow * 64 + bk + 16]);
    __syncthreads();
#pragma unroll
    for (int kk = 0; kk < 2; kk++) {
      int kb = kk * 32 + (lane >> 4) * 8;
      s8v af[4], bfr[4];
#pragma unroll
      for (int m = 0; m < 4; m++)
        af[m] = *(const s8v*)(&Al[(wr * 64 + m * 16 + (lane & 15)) * 64 + kb]);
#pragma unroll
      for (int n = 0; n < 4; n++)
        bfr[n] = *(const s8v*)(&Bl[(wc * 64 + n * 16 + (lane & 15)) * 64 + kb]);
#pragma unroll
      for (int m = 0; m < 4; m++)
#pragma unroll
        for (int n = 0; n < 4; n++)
          acc[m][n] = __builtin_amdgcn_mfma_f32_16x16x32_bf16(af[m], bfr[n], acc[m][n], 0, 0, 0);
    }
    __syncthreads();
  }

#pragma unroll
  for (int m = 0; m < 4; m++) {
#pragma unroll
    for (int r = 0; r < 4; r++) {
      int row = wr * 64 + m * 16 + (lane >> 4) * 4 + r;
      int s = slotbase + row;
      int tok = perm[s];
      if (tok < 0) continue;
      float wv = wgt[s];
      float* op = out + (size_t)tok * D_ + d0 + wc * 64;
#pragma unroll
      for (int n = 0; n < 4; n++)
        atomicAdd(op + n * 16 + (lane & 15), acc[m][n][r] * wv);
    }
  }
}

extern "C" void kernel_launch(void* const* d_in, const int* in_sizes, int n_in,
                              void* d_out, int out_size, void* d_ws, size_t ws_size,
                              hipStream_t stream)
{
  const float* x  = (const float*)d_in[0];
  const float* ew = (const float*)d_in[1];
  const int*  idx = (const int*)d_in[2];
  const float* wg = (const float*)d_in[4];
  const float* wu = (const float*)d_in[5];
  const float* wd = (const float*)d_in[6];
  float* out = (float*)d_out;

  char* ws = (char*)d_ws;
  int* cnt   = (int*)(ws);
  int* ntb   = (int*)(ws + 64);
  int* tb    = (int*)(ws + 128);
  int* offs  = (int*)(ws + 640);
  int* perm  = (int*)(ws + 4096);
  float* wgt = (float*)(ws + 4096 + PADMAX * 4);

  const size_t xb_off  = 131072;
  const size_t xb_b    = (size_t)N_ * D_ * 2;         // 16.78 MB
  const size_t H_b     = (size_t)PADMAX * I_ * 2;     // 83.9 MB
  const size_t w_b     = (size_t)E_ * I_ * D_ * 2;    // 134.2 MB
  unsigned short* xb  = (unsigned short*)(ws + xb_off);
  unsigned short* H   = (unsigned short*)(ws + xb_off + xb_b);
  unsigned short* wgb = (unsigned short*)(ws + xb_off + xb_b + H_b);
  unsigned short* wub = (unsigned short*)((char*)wgb + w_b);
  unsigned short* wdb = (unsigned short*)((char*)wub + w_b);
  size_t need = xb_off + xb_b + H_b + 3 * w_b;        // ~503.4 MB

  hipMemsetAsync(d_out, 0, (size_t)N_ * D_ * sizeof(float), stream);
  cvt8_kernel<<<(N_ * D_ / 8) / 256, 256, 0, stream>>>(x, xb);

  if (ws_size >= need) {
    route_kernel<<<1, 256, 0, stream>>>(idx, ew, 256, cnt, offs, tb, ntb, perm, wgt);
    cvtw_kernel<<<3 * 32768, 256, 0, stream>>>(wg, wu, wd, wgb, wub, wdb);
    gu8_kernel<<<dim3(MAXTB256, I_ / 128), 512, 0, stream>>>(xb, wgb, wub, tb, ntb, offs, perm, H);
    down8_kernel<<<dim3(MAXTB256, D_ / 256), 512, 0, stream>>>(H, wdb, tb, ntb, offs, perm, wgt, out);
  } else {
    route_kernel<<<1, 256, 0, stream>>>(idx, ew, 128, cnt, offs, tb, ntb, perm, wgt);
    gu_f32_kernel<<<dim3(MAXTB128, I_ / 64), 256, 0, stream>>>(xb, wg, wu, tb, ntb, offs, perm, H);
    down_f32_kernel<<<dim3(MAXTB128, D_ / 128), 256, 0, stream>>>(H, wd, tb, ntb, offs, perm, wgt, out);
  }
}